// Round 6
// baseline (156.438 us; speedup 1.0000x reference)
//
#include <hip/hip_runtime.h>
#include <hip/hip_bf16.h>

#define DEVINL __device__ __forceinline__

typedef float  f32x4_t  __attribute__((ext_vector_type(4)));
typedef float  f32x16_t __attribute__((ext_vector_type(16)));
typedef short  bf16x8_t __attribute__((ext_vector_type(8)));

#define MFMA16(a,b,c) __builtin_amdgcn_mfma_f32_16x16x32_bf16((a),(b),(c),0,0,0)
#define MFMA32(a,b,c) __builtin_amdgcn_mfma_f32_32x32x16_bf16((a),(b),(c),0,0,0)

DEVINL unsigned short f2bf(float f) {
  union { float f; unsigned u; } v; v.f = f;
  unsigned r = v.u + 0x7fffu + ((v.u >> 16) & 1u);   // round-to-nearest-even
  return (unsigned short)(r >> 16);
}

DEVINL unsigned pk2bf(float lo, float hi) {          // bf16(lo) | bf16(hi)<<16, RNE
  union { __hip_bfloat162 h2; unsigned u; } v;
  v.h2 = __float22bfloat162_rn(make_float2(lo, hi));
  return v.u;
}

// ============================ fragment-order layouts ============================
// I/J (bf16): idx = (rowtile*8 + mc)*512 + r32*16 + h*8 + e
//   rowtile = (global row)>>5 (I rows: i_l*32+x; J rows: j_l*32+y), r32 = row&31,
//   m = mc*16 + h*8 + e.  A/B frag for 32x32x16 = 16B at (r32=lane&31, h=lane>>5).
// W (bf16): idx = (oT*64 + K16)*512 + o32*16 + h*8 + e; o = oT*32+o32.
//   K-position kpos = K16*16 + h*8 + e carries f-element with kpos = y*32 + x
//   (f = x*32 + y in the reference) — matches fl's kpos order in kB.

// ---------------- kernel A: LayerNorm + proj + split (+ final_w conversion) ------
__global__ __launch_bounds__(256) void kA(const float* __restrict__ x,
                                          const float* __restrict__ nw,
                                          const float* __restrict__ nb,
                                          const float* __restrict__ pw,
                                          const float* __restrict__ pb,
                                          const float* __restrict__ fw,
                                          unsigned short* __restrict__ Wb,
                                          unsigned short* __restrict__ Ig,
                                          unsigned short* __restrict__ Jg) {
  if (blockIdx.x >= 1024) {                  // final_w fp32 -> bf16, kpos = y*32+x
    int T = (blockIdx.x - 1024) * 256 + threadIdx.x;   // 0..32767
    int o     = T >> 8;
    int kpos0 = (T & 255) * 4;               // 4 consecutive kpos (same y, x-run)
    int y  = kpos0 >> 5;
    int x0 = kpos0 & 31;
    const float* fo = fw + o * 1024 + y;
    ushort4 u;
    u.x = f2bf(fo[(x0 + 0) * 32]);
    u.y = f2bf(fo[(x0 + 1) * 32]);
    u.z = f2bf(fo[(x0 + 2) * 32]);
    u.w = f2bf(fo[(x0 + 3) * 32]);
    size_t off = (size_t)((o >> 5) * 64 + (kpos0 >> 4)) * 512 + (o & 31) * 16
               + ((kpos0 >> 3) & 1) * 8 + (kpos0 & 7);
    *(ushort4*)&Wb[off] = u;
    return;
  }
  __shared__ unsigned short xnl[32 * 264];   // 32 m-rows x 256 ch (+8 pad)
  __shared__ unsigned short pwl[64 * 264];   // 64 d x 256 ch (+8 pad)
  __shared__ unsigned short ep[64 * 36];     // transpose buf: [d][m-local]
  const int tid  = threadIdx.x;
  const int wv   = tid >> 6;
  const int lane = tid & 63;
  const int q    = lane >> 4;
  const int ln16 = lane & 15;
  const int l    = blockIdx.x & 255;
  const int m0   = (blockIdx.x >> 8) * 32;

  const float4* xs = (const float4*)x;
  float4 v[8];
#pragma unroll
  for (int i = 0; i < 8; i++) {
    int row = m0 + i * 4 + wv;
    v[i] = xs[row * 16384 + l * 64 + lane];
  }
  float4 nw4 = ((const float4*)nw)[lane];
  float4 nb4 = ((const float4*)nb)[lane];

#pragma unroll
  for (int i = 0; i < 8; i++) {
    float s  = v[i].x + v[i].y + v[i].z + v[i].w;
    float ss = v[i].x * v[i].x + v[i].y * v[i].y + v[i].z * v[i].z + v[i].w * v[i].w;
#pragma unroll
    for (int off = 32; off > 0; off >>= 1) {
      s  += __shfl_xor(s, off);
      ss += __shfl_xor(ss, off);
    }
    float mu  = s * (1.0f / 256.0f);
    float var = ss * (1.0f / 256.0f) - mu * mu;
    float rs  = rsqrtf(var + 1e-5f);
    ushort4 u;
    u.x = f2bf((v[i].x - mu) * rs * nw4.x + nb4.x);
    u.y = f2bf((v[i].y - mu) * rs * nw4.y + nb4.y);
    u.z = f2bf((v[i].z - mu) * rs * nw4.z + nb4.z);
    u.w = f2bf((v[i].w - mu) * rs * nw4.w + nb4.w);
    *(ushort4*)&xnl[(i * 4 + wv) * 264 + lane * 4] = u;
  }

  const float4* ps = (const float4*)pw;
#pragma unroll
  for (int i = 0; i < 16; i++) {
    float4 w4 = ps[i * 256 + tid];
    ushort4 u;
    u.x = f2bf(w4.x); u.y = f2bf(w4.y); u.z = f2bf(w4.z); u.w = f2bf(w4.w);
    *(ushort4*)&pwl[(i * 4 + wv) * 264 + lane * 4] = u;
  }
  __syncthreads();

  const int rt = wv & 1;
  const int db = (wv >> 1) * 32;
  f32x4_t acc[2] = {{0.f, 0.f, 0.f, 0.f}, {0.f, 0.f, 0.f, 0.f}};
#pragma unroll
  for (int kc = 0; kc < 8; kc++) {
    bf16x8_t a  = *(const bf16x8_t*)&xnl[(rt * 16 + ln16) * 264 + kc * 32 + q * 8];
    bf16x8_t b0 = *(const bf16x8_t*)&pwl[(db + ln16) * 264 + kc * 32 + q * 8];
    bf16x8_t b1 = *(const bf16x8_t*)&pwl[(db + 16 + ln16) * 264 + kc * 32 + q * 8];
    acc[0] = MFMA16(a, b0, acc[0]);
    acc[1] = MFMA16(a, b1, acc[1]);
  }

#pragma unroll
  for (int t2 = 0; t2 < 2; t2++) {
    int d = db + t2 * 16 + ln16;
    float bias  = pb[d];
    float scale = (d & 1) ? 1.0f : (1.0f / 128.0f);
#pragma unroll
    for (int r = 0; r < 4; r++) {
      int mloc = rt * 16 + q * 4 + r;
      ep[d * 36 + mloc] = f2bf((acc[t2][r] + bias) * scale);
    }
  }
  __syncthreads();

  // frag-order stores: I from even d (h row = x), J from odd d.
  const int h  = tid >> 3;          // 0..31 (x or y)
  const int m4 = tid & 7;           // m = m0 + m4*4
  const size_t off = (size_t)(l * 8 + (m0 >> 4) + (m4 >> 2)) * 512 + h * 16 + ((m4 >> 1) & 1) * 8 + (m4 & 1) * 4;
  ushort4 vi = *(const ushort4*)&ep[(2 * h) * 36 + m4 * 4];
  *(ushort4*)&Ig[off] = vi;
  ushort4 vj = *(const ushort4*)&ep[(2 * h + 1) * 36 + m4 * 4];
  *(ushort4*)&Jg[off] = vj;
}

// ---------------- kernel B: fused outer-product-mean + final GEMM ----------------
// 1024 blocks x 512 thr; block = (p: 4 i_l) x (t: 16 j_l). fl[64][1048] bf16.
// 3-phase jl-parity ping-pong:
//   P0: GEMM1 even jl          | W-ring prefill        | barrier
//   P1: GEMM1 odd jl  ‖  GEMM2 on even rows            | ring refill | barrier
//   P2: GEMM2 on odd rows                              | barrier
//   reduction over K-quarters (scalar f32, bank-aligned) + epilogue.
// GEMM2 wave = (ow = o-half, kq = K-quarter): each A-frag read feeds 2 MFMAs.
__global__ __launch_bounds__(512, 2) void kB(const unsigned short* __restrict__ Ig,
                                             const unsigned short* __restrict__ Jg,
                                             const unsigned short* __restrict__ Wb,
                                             const float* __restrict__ fb,
                                             float* __restrict__ out) {
  extern __shared__ unsigned short fl[];     // 64 x 1048
  constexpr int P = 1048;
  const int tid  = threadIdx.x;
  const int w    = tid >> 6;                 // wave 0..7
  const int lane = tid & 63;
  const int ln32 = lane & 31;
  const int h    = lane >> 5;
  const int p    = blockIdx.x >> 4;          // i_l quad
  const int t    = blockIdx.x & 15;          // 16-jl tile

  const unsigned short* Ibase = Ig + (size_t)(p * 32) * 512 + ln32 * 16 + h * 8;
  const unsigned short* Jb    = Jg + (size_t)(t * 16) * 4096 + ln32 * 16 + h * 8;

  // ---- GEMM1 worker: one jl (wave-owned), writes fl rows il*16+jl ----
  auto gemm1 = [&](int jl, const bf16x8_t* jb) {
#pragma unroll
    for (int ilp = 0; ilp < 2; ilp++) {
      bf16x8_t af[2][8];
#pragma unroll
      for (int u = 0; u < 2; u++)
#pragma unroll
        for (int mc = 0; mc < 8; mc++)
          af[u][mc] = *(const bf16x8_t*)&Ibase[(size_t)((ilp * 2 + u) * 8 + mc) * 512];
      f32x16_t c[2];
#pragma unroll
      for (int i = 0; i < 16; i++) { c[0][i] = 0.f; c[1][i] = 0.f; }
#pragma unroll
      for (int mc = 0; mc < 8; mc++) {
        c[0] = MFMA32(af[0][mc], jb[mc], c[0]);
        c[1] = MFMA32(af[1][mc], jb[mc], c[1]);
      }
      // lane col y=ln32; reg quad g -> x = 8g+4h..+3; chunk c=4y+g, swz c^((c>>2)&7)
#pragma unroll
      for (int u = 0; u < 2; u++) {
        unsigned short* fr = &fl[((ilp * 2 + u) * 16 + jl) * P];
#pragma unroll
        for (int g = 0; g < 4; g++) {
          int cp = (4 * ln32 + g) ^ (ln32 & 7);
          uint2 pv;
          pv.x = pk2bf(c[u][4 * g + 0], c[u][4 * g + 1]);
          pv.y = pk2bf(c[u][4 * g + 2], c[u][4 * g + 3]);
          *(uint2*)&fr[cp * 8 + h * 4] = pv;
        }
      }
    }
  };

  // ---- GEMM2 role: ow = o-half (2 o-tiles), kq = K-quarter (16 K16-steps) ----
  const int ow = w & 1;
  const int kq = w >> 1;
  const unsigned short* Wp = Wb + ((size_t)(ow * 2) * 64 + kq * 16) * 512 + ln32 * 16 + h * 8;
  const unsigned short* ar0 = &fl[((ln32 >> 3) * 16 + 2 * (ln32 & 7)) * P];

  auto gemm2h = [&](int par, f32x16_t& d0, f32x16_t& d1, bf16x8_t wr[2][4]) {
    const unsigned short* ar = ar0 + par * P;
    auto lda = [&](int kc) {
      int K16 = kq * 16 + kc;
      int c2  = K16 * 2 + h;
      int cps = c2 ^ ((K16 >> 1) & 7);
      return *(const bf16x8_t*)&ar[cps * 8];
    };
    bf16x8_t a0 = lda(0), a1 = lda(1);
#pragma unroll
    for (int kc = 0; kc < 16; kc++) {
      bf16x8_t ac = a0;
      a0 = a1;
      if (kc < 14) a1 = lda(kc + 2);
      bf16x8_t b0 = wr[0][kc & 3], b1 = wr[1][kc & 3];
      if (kc < 12) {
        wr[0][kc & 3] = *(const bf16x8_t*)&Wp[(kc + 4) * 512];
        wr[1][kc & 3] = *(const bf16x8_t*)&Wp[32768 + (kc + 4) * 512];
      }
      d0 = MFMA32(ac, b0, d0);
      d1 = MFMA32(ac, b1, d1);
    }
  };

  // ================= phase 0: GEMM1 even jl =================
  bf16x8_t jbE[8], jbO[8];
#pragma unroll
  for (int mc = 0; mc < 8; mc++) jbE[mc] = *(const bf16x8_t*)&Jb[(size_t)(2 * w) * 4096 + mc * 512];
#pragma unroll
  for (int mc = 0; mc < 8; mc++) jbO[mc] = *(const bf16x8_t*)&Jb[(size_t)(2 * w + 1) * 4096 + mc * 512];

  gemm1(2 * w, jbE);

  bf16x8_t wr[2][4];                          // W ring prefill (pre-barrier)
#pragma unroll
  for (int d = 0; d < 4; d++) {
    wr[0][d] = *(const bf16x8_t*)&Wp[d * 512];
    wr[1][d] = *(const bf16x8_t*)&Wp[32768 + d * 512];
  }
  __syncthreads();

  // ================= phase 1: GEMM1 odd ‖ GEMM2 even rows =================
  gemm1(2 * w + 1, jbO);

  f32x16_t oE0, oE1, oO0, oO1;
#pragma unroll
  for (int i = 0; i < 16; i++) { oE0[i] = 0.f; oE1[i] = 0.f; oO0[i] = 0.f; oO1[i] = 0.f; }
  gemm2h(0, oE0, oE1, wr);

#pragma unroll
  for (int d = 0; d < 4; d++) {              // ring refill for odd half (pre-barrier)
    wr[0][d] = *(const bf16x8_t*)&Wp[d * 512];
    wr[1][d] = *(const bf16x8_t*)&Wp[32768 + d * 512];
  }
  __syncthreads();

  // ================= phase 2: GEMM2 odd rows =================
  gemm2h(1, oO0, oO1, wr);
  __syncthreads();                            // all fl reads done

  // ======= K-quarter reduction (scalar f32, bank-aligned) + epilogue =======
  float* red = (float*)fl;                    // 3 parts x 64 rows x 128 o = 96 KB
  if (kq > 0) {
    const int part = kq - 1;
#pragma unroll
    for (int par = 0; par < 2; par++)
#pragma unroll
      for (int ots = 0; ots < 2; ots++) {
        const f32x16_t& d = par ? (ots ? oO1 : oO0) : (ots ? oE1 : oE0);
        float* bb = red + part * 8192 + par * 4096 + (ow * 2 + ots) * 32 + ln32;
#pragma unroll
        for (int r = 0; r < 16; r++) {
          int rr = (r & 3) + 8 * (r >> 2) + 4 * h;
          bb[rr * 128] = d[r];
        }
      }
  }
  __syncthreads();
  if (kq == 0) {
#pragma unroll
    for (int par = 0; par < 2; par++)
#pragma unroll
      for (int ots = 0; ots < 2; ots++) {
        const f32x16_t& d = par ? (ots ? oO1 : oO0) : (ots ? oE1 : oE0);
        const int o = (ow * 2 + ots) * 32 + ln32;
        const float bias = fb[o];
        const float* bb = red + par * 4096 + (ow * 2 + ots) * 32 + ln32;
#pragma unroll
        for (int r = 0; r < 16; r++) {
          int rr = (r & 3) + 8 * (r >> 2) + 4 * h;
          float val = d[r] + bias + bb[rr * 128] + bb[8192 + rr * 128] + bb[16384 + rr * 128];
          int il = rr >> 3, jl = 2 * (rr & 7) + par;
          out[((size_t)(p * 4 + il) * 256 + t * 16 + jl) * 128 + o] = val;
        }
      }
  }
}

extern "C" void kernel_launch(void* const* d_in, const int* in_sizes, int n_in,
                              void* d_out, int out_size, void* d_ws, size_t ws_size,
                              hipStream_t stream) {
  const float* x1d     = (const float*)d_in[0];
  const float* norm_w  = (const float*)d_in[1];
  const float* norm_b  = (const float*)d_in[2];
  const float* proj_w  = (const float*)d_in[3];
  const float* proj_b  = (const float*)d_in[4];
  const float* final_w = (const float*)d_in[5];
  const float* final_b = (const float*)d_in[6];
  float* outp          = (float*)d_out;

  // workspace carve (bf16): W (128*1024), I (256*32*128), J (256*32*128)
  unsigned short* Wb  = (unsigned short*)d_ws;
  unsigned short* Igp = Wb + 131072;
  unsigned short* Jgp = Igp + 1048576;

  const int kb_lds = 64 * 1048 * 2;   // 134144 B -> 1 block/CU
  hipFuncSetAttribute((const void*)kB, hipFuncAttributeMaxDynamicSharedMemorySize, kb_lds);

  kA<<<1152, 256, 0, stream>>>(x1d, norm_w, norm_b, proj_w, proj_b, final_w, Wb, Igp, Jgp);
  kB<<<1024, 512, kb_lds, stream>>>(Igp, Jgp, Wb, final_b, outp);
}